// Round 3
// baseline (17799.336 us; speedup 1.0000x reference)
//
#include <hip/hip_runtime.h>
#include <hip/hip_fp16.h>

#define TT   2048
#define EMBD 256
#define HD   256      // H2
#define NG   1024     // 4*H2
#define NC   12
#define NEGV -10000.0f

typedef _Float16 half2v __attribute__((ext_vector_type(2)));
typedef _Float16 f16x8  __attribute__((ext_vector_type(8)));
typedef float    f32x4  __attribute__((ext_vector_type(4)));

// ---- static device scratch ----
__device__ float g_P[2 * TT * NG];   // input-GEMM preactivations, permuted: gate ga of unit u at 4u+ga (16 MB)
__device__ float g_HS[2 * TT * HD];  // hidden states both dirs (4 MB)
__device__ float g_FE[TT * NC];      // CRF emission feats (96 KB)
__device__ unsigned short g_HX[2 * 2 * TT * 128];  // per (d,half,it): 128 h f16 exchange payload (2 MB)
__device__ unsigned int   g_FL[2 * 2 * TT * 2];    // per (d,half,it,wave): epoch flag (64 KB)
__device__ unsigned int   g_epoch;                 // bumped once per launch by k_input

__device__ __forceinline__ unsigned int f2h2(float a, float b) {
  half2v h; h.x = (_Float16)a; h.y = (_Float16)b;
  return __builtin_bit_cast(unsigned int, h);
}
__device__ __forceinline__ f16x8 asf16x8(uint4 v) { return __builtin_bit_cast(f16x8, v); }
__device__ __forceinline__ float fsigmoid(float x) { return 1.0f / (1.0f + __expf(-x)); }
__device__ __forceinline__ float ftanh(float x) {
  float a = fabsf(x);
  float e = __expf(-2.0f * a);
  float r = (1.0f - e) / (1.0f + e);
  return copysignf(r, x);
}

// Row permutation shared by k_input (writer) and k_rec (reader):
// original gate-row g = ga*256 + u  ->  permuted row r' = 4*u + ga
// (so P for unit u is one contiguous float4 = (i,f,g,o))

// ---------------- K1: embedding gather + input GEMM (+ both biases), f32 ----------------
__global__ __launch_bounds__(256) void k_input(
    const int* __restrict__ sent, const float* __restrict__ emb,
    const float* __restrict__ WihF, const float* __restrict__ bihF,
    const float* __restrict__ bhhF,
    const float* __restrict__ WihB, const float* __restrict__ bihB,
    const float* __restrict__ bhhB)
{
  if (blockIdx.x == 0 && threadIdx.x == 0) atomicAdd(&g_epoch, 1u);  // run epoch for k_rec flags
  const int d  = blockIdx.x & 1;
  const int t0 = (blockIdx.x >> 1) * 16;
  const float* Wih = d ? WihB : WihF;
  const float* bih = d ? bihB : bihF;
  const float* bhh = d ? bhhB : bhhF;
  __shared__ float xs[16][EMBD];
  for (int i = threadIdx.x; i < 16 * (EMBD / 4); i += 256) {
    const int tt = i >> 6, e4 = i & 63;
    reinterpret_cast<float4*>(xs[tt])[e4] =
        reinterpret_cast<const float4*>(emb + (size_t)sent[t0 + tt] * EMBD)[e4];
  }
  __syncthreads();
  for (int gg = 0; gg < 4; ++gg) {
    const int g = threadIdx.x + gg * 256;
    const float bias = bih[g] + bhh[g];
    float acc[16];
#pragma unroll
    for (int tt = 0; tt < 16; ++tt) acc[tt] = 0.0f;
    const float* wr = Wih + (size_t)g * EMBD;
    for (int e = 0; e < EMBD; e += 4) {
      const float4 w = *reinterpret_cast<const float4*>(wr + e);
#pragma unroll
      for (int tt = 0; tt < 16; ++tt) {
        acc[tt] += w.x * xs[tt][e] + w.y * xs[tt][e + 1]
                 + w.z * xs[tt][e + 2] + w.w * xs[tt][e + 3];
      }
    }
    const int u = g & 255, ga = g >> 8;
    const int rp = 4 * u + ga;            // permuted row
    float* Pg = g_P + ((size_t)d * TT + t0) * NG + rp;
#pragma unroll
    for (int tt = 0; tt < 16; ++tt) Pg[(size_t)tt * NG] = acc[tt] + bias;
  }
}

// ---------------- K2: BiLSTM recurrence — 2 CUs per direction, fully register-resident weights ----
// 4 blocks: block (d, x) owns units [x*128, x*128+128) of direction d.
// 512 threads (8 waves, 2/SIMD). Per wave: 4 rowtiles x 8 k-tiles, all resident (128 VGPR).
// Per step: own-half B from LDS; partner half h exchanged via LLC (sc0 sc1) with
// per-step epoch flags. Flag posted at top of next step (payload drains under barrier).
__global__ __launch_bounds__(512, 2) void k_rec(
    const float* __restrict__ WhhF, const float* __restrict__ WhhB,
    const float* __restrict__ h0g, const float* __restrict__ c0g)
{
  __shared__ __align__(16) unsigned short h2[2][256];  // f16 h (full 256), double buffered
  __shared__ __align__(16) float gates[128][4];        // (i,f,g,o) per local unit

  const int bid = blockIdx.x;
  const int d = bid >> 1, x = bid & 1;
  const float* __restrict__ Whh = d ? WhhB : WhhF;
  const int tid  = threadIdx.x;
  const int w    = tid >> 6;
  const int lane = tid & 63;
  const int kg   = lane >> 4;        // k-group 0..3 (A/B: k = kt*32 + kg*8 + j)
  const int m    = lane & 15;        // A-row within 16-tile (m = lg*4 + ga)
  const int lg   = m >> 2, ga = m & 3;
  const int okt0 = x * 4;            // own k-tiles cover own units' h
  const int pkt0 = 4 - okt0;         // partner k-tiles

  const unsigned int ep =
      __hip_atomic_load(&g_epoch, __ATOMIC_RELAXED, __HIP_MEMORY_SCOPE_AGENT);

  // ---- pack A fragments f32 -> f16: ALL resident (4 rt x 8 kt x 4 regs = 128) ----
  uint4 Ares[4][8];
#pragma unroll
  for (int rtl = 0; rtl < 4; ++rtl) {
    const int u = x * 128 + (w << 4) + (rtl << 2) + lg;   // global unit of this A-row
    const int orow = (ga << 8) + u;                        // original Whh row
    const float* wr = Whh + (size_t)orow * HD;
#pragma unroll
    for (int kt = 0; kt < 8; ++kt) {
      const int k0 = (kt << 5) + (kg << 3);
      const float4 x0 = *reinterpret_cast<const float4*>(wr + k0);
      const float4 x1 = *reinterpret_cast<const float4*>(wr + k0 + 4);
      uint4 f;
      f.x = f2h2(x0.x, x0.y); f.y = f2h2(x0.z, x0.w);
      f.z = f2h2(x1.x, x1.y); f.w = f2h2(x1.z, x1.w);
      Ares[rtl][kt] = f;
    }
  }
  if (tid < 128)   // full h0 (both halves) into h2[0]
    reinterpret_cast<unsigned int*>(h2[0])[tid] =
        f2h2(h0g[d * HD + 2 * tid], h0g[d * HD + 2 * tid + 1]);
  float c = (tid < 128) ? c0g[d * HD + x * 128 + tid] : 0.0f;
  __syncthreads();

  const float* Pbase = g_P + (size_t)d * TT * NG + 4 * (x * 128 + tid);  // tid<128
  unsigned short*       payW = g_HX + (size_t)((d * 2 + x) * TT) * 128;
  const unsigned short* payR = g_HX + (size_t)((d * 2 + (x ^ 1)) * TT) * 128;
  unsigned int*         flW  = g_FL + (size_t)(d * 2 + x) * TT * 2;
  const unsigned int*   flR  = g_FL + (size_t)(d * 2 + (x ^ 1)) * TT * 2;

  int t = d ? (TT - 1) : 0;
  const int tstep = d ? -1 : 1;
  float4 Pc = {0.f, 0.f, 0.f, 0.f};
  if (tid < 128) Pc = *reinterpret_cast<const float4*>(Pbase + (size_t)t * NG);
  int p = 0;

  for (int it = 0; it < TT; ++it, t += tstep) {
    uint2 fl = {0u, 0u};
    if (it > 0) {
      // post OUR flag for step it-1 (payload stores drained by now), THEN poll partner.
      // post-before-poll => deadlock-free by induction.
      if (tid < 128) {
        asm volatile("s_waitcnt vmcnt(0)" ::: "memory");
        if (lane == 0) {
          unsigned int* fp = flW + (size_t)(it - 1) * 2 + w;
          asm volatile("global_store_dword %0, %1, off sc0 sc1"
                       :: "v"(fp), "v"(ep) : "memory");
        }
      }
      const unsigned int* pp = flR + (size_t)(it - 1) * 2;
      asm volatile("global_load_dwordx2 %0, %1, off sc0 sc1"    // async; checked in phase B
                   : "=v"(fl) : "v"(pp) : "memory");
      __builtin_amdgcn_sched_barrier(0);
    }

    // ---- phase A: own-half B-frags (LDS broadcast) + own-kt MFMAs (hides flag latency) ----
    f32x4 acc[4] = {{0.f,0.f,0.f,0.f},{0.f,0.f,0.f,0.f},{0.f,0.f,0.f,0.f},{0.f,0.f,0.f,0.f}};
    {
      f16x8 bfo[4];
#pragma unroll
      for (int i = 0; i < 4; ++i)
        bfo[i] = asf16x8(*reinterpret_cast<const uint4*>(
            &h2[p][((okt0 + i) << 5) + (kg << 3)]));
#pragma unroll
      for (int rtl = 0; rtl < 4; ++rtl)
#pragma unroll
        for (int i = 0; i < 4; ++i)
          acc[rtl] = __builtin_amdgcn_mfma_f32_16x16x32_f16(
              asf16x8(Ares[rtl][okt0 + i]), bfo[i], acc[rtl], 0, 0, 0);
    }

    // ---- phase B: partner-half B-frags ----
    uint4 pb[4];
    if (it == 0) {
#pragma unroll
      for (int i = 0; i < 4; ++i)
        pb[i] = *reinterpret_cast<const uint4*>(&h2[0][((pkt0 + i) << 5) + (kg << 3)]);
    } else {
      asm volatile("s_waitcnt vmcnt(0)" : "+v"(fl) :: "memory");  // tie: no use-before-wait
      __builtin_amdgcn_sched_barrier(0);
      while (fl.x != ep || fl.y != ep) {
        const unsigned int* pp = flR + (size_t)(it - 1) * 2;
        asm volatile("global_load_dwordx2 %0, %1, off sc0 sc1\n\ts_waitcnt vmcnt(0)"
                     : "=v"(fl) : "v"(pp) : "memory");
      }
      const unsigned short* pr = payR + (size_t)(it - 1) * 128 + (kg << 3);
      asm volatile(
          "global_load_dwordx4 %0, %4, off sc0 sc1\n\t"
          "global_load_dwordx4 %1, %4, off offset:64 sc0 sc1\n\t"
          "global_load_dwordx4 %2, %4, off offset:128 sc0 sc1\n\t"
          "global_load_dwordx4 %3, %4, off offset:192 sc0 sc1\n\t"
          "s_waitcnt vmcnt(0)"
          : "=v"(pb[0]), "=v"(pb[1]), "=v"(pb[2]), "=v"(pb[3])
          : "v"(pr) : "memory");
      __builtin_amdgcn_sched_barrier(0);
    }
#pragma unroll
    for (int rtl = 0; rtl < 4; ++rtl)
#pragma unroll
      for (int i = 0; i < 4; ++i)
        acc[rtl] = __builtin_amdgcn_mfma_f32_16x16x32_f16(
            asf16x8(Ares[rtl][pkt0 + i]), asf16x8(pb[i]), acc[rtl], 0, 0, 0);

    // ---- phase D: gates to LDS (D row = kg*4+reg -> local unit w*16+rtl*4+kg) ----
    if (m == 0) {
#pragma unroll
      for (int rtl = 0; rtl < 4; ++rtl)
        *reinterpret_cast<float4*>(gates[(w << 4) + (rtl << 2) + kg]) =
            __builtin_bit_cast(float4, acc[rtl]);
    }
    asm volatile("s_waitcnt lgkmcnt(0)" ::: "memory");
    __builtin_amdgcn_s_barrier();
    __builtin_amdgcn_sched_barrier(0);

    // ---- phase E: cell update, one lane per local unit (tid<128) ----
    if (tid < 128) {
      const float4 gv = *reinterpret_cast<const float4*>(gates[tid]);
      const float gi = gv.x + Pc.x;
      const float gf = gv.y + Pc.y;
      const float gz = gv.z + Pc.z;
      const float go = gv.w + Pc.w;
      c = fsigmoid(gf) * c + fsigmoid(gi) * ftanh(gz);
      const float hh = fsigmoid(go) * ftanh(c);
      g_HS[((size_t)d * TT + t) * HD + x * 128 + tid] = hh;          // f32 for feats
      h2[p ^ 1][x * 128 + tid] = __builtin_bit_cast(unsigned short, (_Float16)hh);
      // payload for partner (flag posted at next step's top, after vmcnt drain)
      unsigned short* pw = payW + (size_t)it * 128 + tid;
      const unsigned int hbits =
          (unsigned int)__builtin_bit_cast(unsigned short, (_Float16)hh);
      asm volatile("global_store_short %0, %1, off sc0 sc1"
                   :: "v"(pw), "v"(hbits) : "memory");
      // reload P for next step: a full step of latency cover
      const int tn = (it + 1 < TT) ? (t + tstep) : t;
      Pc = *reinterpret_cast<const float4*>(Pbase + (size_t)tn * NG);
    }
    p ^= 1;
    // barrier 2: h2 ready for next step's own-half reads (LDS-only drain)
    asm volatile("s_waitcnt lgkmcnt(0)" ::: "memory");
    __builtin_amdgcn_s_barrier();
    __builtin_amdgcn_sched_barrier(0);
  }
}

// ---------------- K3: feats = [hf;hb] @ Wlin^T + blin (pure f32) ----------------
__global__ __launch_bounds__(256) void k_feats(
    const float* __restrict__ Wlin, const float* __restrict__ blin)
{
  const int gid = blockIdx.x * 256 + threadIdx.x;
  if (gid >= TT * NC) return;
  const int t = gid / NC, cc = gid - t * NC;
  const float* hf = g_HS + (size_t)t * HD;
  const float* hb = g_HS + ((size_t)TT + t) * HD;
  const float* wr = Wlin + cc * 512;
  float acc = blin[cc];
  for (int j = 0; j < HD; j += 4) {
    const float4 w = *reinterpret_cast<const float4*>(wr + j);
    acc += w.x * hf[j] + w.y * hf[j + 1] + w.z * hf[j + 2] + w.w * hf[j + 3];
  }
  for (int j = 0; j < HD; j += 4) {
    const float4 w = *reinterpret_cast<const float4*>(wr + 256 + j);
    acc += w.x * hb[j] + w.y * hb[j + 1] + w.z * hb[j + 2] + w.w * hb[j + 3];
  }
  g_FE[gid] = acc;
}

// ---------------- K4: Viterbi + backtrace (single wave); f32 in/out ----------------
__global__ __launch_bounds__(64) void k_vit(
    const float* __restrict__ trans, float* __restrict__ out)
{
  const int lane = threadIdx.x;
  const bool act = lane < NC;
  __shared__ unsigned char bp[TT][NC];
  float Trow[NC];
#pragma unroll
  for (int i = 0; i < NC; ++i) Trow[i] = act ? trans[lane * NC + i] : NEGV;
  float fv[NC];
#pragma unroll
  for (int i = 0; i < NC; ++i) fv[i] = (i == 10) ? 0.0f : NEGV;  // START=10

  float f0 = act ? g_FE[lane] : 0.0f;                 // 2-deep FE prefetch
  float f1 = act ? g_FE[NC + lane] : 0.0f;
  for (int t = 0; t < TT; ++t) {
    const float feat = f0;
    f0 = f1;
    f1 = (act && t + 2 < TT) ? g_FE[(t + 2) * NC + lane] : 0.0f;
    float best = fv[0] + Trow[0]; int bi = 0;
#pragma unroll
    for (int i = 1; i < NC; ++i) {
      const float s = fv[i] + Trow[i];
      if (s > best) { best = s; bi = i; }   // strict > == jnp first-max tiebreak
    }
    if (act) bp[t][lane] = (unsigned char)bi;
    const float nf = best + feat;
#pragma unroll
    for (int i = 0; i < NC; ++i) fv[i] = __shfl(nf, i);
  }
  // terminal = fv + transitions[STOP=11] (row 11)
  const float term = act ? (fv[lane] + trans[11 * NC + lane]) : -3.0e38f;
  float tv[NC];
#pragma unroll
  for (int i = 0; i < NC; ++i) tv[i] = __shfl(term, i);
  if (lane == 0) {
    float bs = tv[0]; int bt = 0;
#pragma unroll
    for (int i = 1; i < NC; ++i) if (tv[i] > bs) { bs = tv[i]; bt = i; }
    out[0] = bs;                             // f32 path_score
    int tag = bt;
    for (int t = TT - 1; t >= 0; --t) {
      out[1 + t] = (float)tag;               // path tags as f32
      tag = bp[t][tag];
    }
  }
}

extern "C" void kernel_launch(void* const* d_in, const int* in_sizes, int n_in,
                              void* d_out, int out_size, void* d_ws, size_t ws_size,
                              hipStream_t stream) {
  const int*   sent = (const int*)d_in[0];
  const float* emb  = (const float*)d_in[1];
  const float* WihF = (const float*)d_in[2];
  const float* WhhF = (const float*)d_in[3];
  const float* bihF = (const float*)d_in[4];
  const float* bhhF = (const float*)d_in[5];
  const float* WihB = (const float*)d_in[6];
  const float* WhhB = (const float*)d_in[7];
  const float* bihB = (const float*)d_in[8];
  const float* bhhB = (const float*)d_in[9];
  const float* Wlin = (const float*)d_in[10];
  const float* blin = (const float*)d_in[11];
  const float* h0g  = (const float*)d_in[12];
  const float* c0g  = (const float*)d_in[13];
  const float* trans= (const float*)d_in[14];
  (void)d_ws; (void)ws_size; (void)in_sizes; (void)n_in; (void)out_size;

  k_input<<<dim3(2 * (TT / 16)), dim3(256), 0, stream>>>(
      sent, emb, WihF, bihF, bhhF, WihB, bihB, bhhB);

  k_rec<<<dim3(4), dim3(512), 0, stream>>>(WhhF, WhhB, h0g, c0g);

  k_feats<<<dim3((TT * NC + 255) / 256), dim3(256), 0, stream>>>(Wlin, blin);

  k_vit<<<dim3(1), dim3(64), 0, stream>>>(trans, (float*)d_out);
}

// Round 4
// 4898.589 us; speedup vs baseline: 3.6336x; 3.6336x over previous
//
#include <hip/hip_runtime.h>
#include <hip/hip_fp16.h>

#define TT   2048
#define EMBD 256
#define HD   256      // H2
#define NG   1024     // 4*H2
#define NC   12
#define NEGV -10000.0f

typedef _Float16 half2v __attribute__((ext_vector_type(2)));
typedef _Float16 f16x8  __attribute__((ext_vector_type(8)));
typedef float    f32x4  __attribute__((ext_vector_type(4)));

// ---- static device scratch ----
__device__ float g_P[2 * TT * NG];   // input-GEMM preactivations, permuted: gate ga of unit u at 4u+ga (16 MB)
__device__ float g_HS[2 * TT * HD];  // hidden states both dirs (4 MB)
__device__ float g_FE[TT * NC];      // CRF emission feats (96 KB)
__device__ unsigned short g_HX[2 * 2 * TT * 128];  // per (d,half,it): 128 h f16 exchange payload (2 MB)
__device__ unsigned int   g_FL[2 * 2 * TT * 2];    // per (d,half,it,wave): epoch flag (64 KB)
__device__ unsigned int   g_epoch;                 // bumped once per launch by k_input

__device__ __forceinline__ unsigned int f2h2(float a, float b) {
  half2v h; h.x = (_Float16)a; h.y = (_Float16)b;
  return __builtin_bit_cast(unsigned int, h);
}
__device__ __forceinline__ f16x8 asf16x8(uint4 v) { return __builtin_bit_cast(f16x8, v); }
__device__ __forceinline__ float fsigmoid(float x) { return 1.0f / (1.0f + __expf(-x)); }
__device__ __forceinline__ float ftanh(float x) {
  float a = fabsf(x);
  float e = __expf(-2.0f * a);
  float r = (1.0f - e) / (1.0f + e);
  return copysignf(r, x);
}

// Row permutation shared by k_input (writer) and k_rec (reader):
// original gate-row g = ga*256 + u  ->  permuted row r' = 4*u + ga
// (so P for unit u is one contiguous float4 = (i,f,g,o))

// ---------------- K1: embedding gather + input GEMM (+ both biases), f32 ----------------
__global__ __launch_bounds__(256) void k_input(
    const int* __restrict__ sent, const float* __restrict__ emb,
    const float* __restrict__ WihF, const float* __restrict__ bihF,
    const float* __restrict__ bhhF,
    const float* __restrict__ WihB, const float* __restrict__ bihB,
    const float* __restrict__ bhhB)
{
  if (blockIdx.x == 0 && threadIdx.x == 0) atomicAdd(&g_epoch, 1u);  // run epoch for k_rec flags
  const int d  = blockIdx.x & 1;
  const int t0 = (blockIdx.x >> 1) * 16;
  const float* Wih = d ? WihB : WihF;
  const float* bih = d ? bihB : bihF;
  const float* bhh = d ? bhhB : bhhF;
  __shared__ float xs[16][EMBD];
  for (int i = threadIdx.x; i < 16 * (EMBD / 4); i += 256) {
    const int tt = i >> 6, e4 = i & 63;
    reinterpret_cast<float4*>(xs[tt])[e4] =
        reinterpret_cast<const float4*>(emb + (size_t)sent[t0 + tt] * EMBD)[e4];
  }
  __syncthreads();
  for (int gg = 0; gg < 4; ++gg) {
    const int g = threadIdx.x + gg * 256;
    const float bias = bih[g] + bhh[g];
    float acc[16];
#pragma unroll
    for (int tt = 0; tt < 16; ++tt) acc[tt] = 0.0f;
    const float* wr = Wih + (size_t)g * EMBD;
    for (int e = 0; e < EMBD; e += 4) {
      const float4 w = *reinterpret_cast<const float4*>(wr + e);
#pragma unroll
      for (int tt = 0; tt < 16; ++tt) {
        acc[tt] += w.x * xs[tt][e] + w.y * xs[tt][e + 1]
                 + w.z * xs[tt][e + 2] + w.w * xs[tt][e + 3];
      }
    }
    const int u = g & 255, ga = g >> 8;
    const int rp = 4 * u + ga;            // permuted row
    float* Pg = g_P + ((size_t)d * TT + t0) * NG + rp;
#pragma unroll
    for (int tt = 0; tt < 16; ++tt) Pg[(size_t)tt * NG] = acc[tt] + bias;
  }
}

// ---------------- K2: BiLSTM recurrence — 2 CUs per direction, register-resident weights ----
// 4 blocks: block (d, X) owns units [X*128, X*128+128) of direction d.
// 512 threads (8 waves, 2/SIMD). Per wave: 4 rowtiles x 8 k-tiles, all resident (128 VGPR).
// X is a TEMPLATE parameter so every Ares[][] index is compile-time (round-3 spill fix).
// Cross-CU h exchange via LLC (sc0 sc1) with per-step epoch flags; release pattern:
// payload store -> vmcnt(0) -> flag store, all inside phase E (earliest possible post).
template<int X>
__device__ __forceinline__ void rec_body(
    const int d, const float* __restrict__ Whh,
    const float* __restrict__ h0g, const float* __restrict__ c0g,
    unsigned short (*h2)[256], float (*gates)[4])
{
  constexpr int okt0 = X * 4;        // own k-tiles (cover own units' h slice)
  constexpr int pkt0 = 4 - okt0;     // partner k-tiles

  const int tid  = threadIdx.x;
  const int w    = tid >> 6;
  const int lane = tid & 63;
  const int kg   = lane >> 4;        // k-group 0..3 (A/B: k = kt*32 + kg*8 + j)
  const int m    = lane & 15;        // A-row within 16-tile (m = lg*4 + ga)
  const int lg   = m >> 2, ga = m & 3;

  const unsigned int ep =
      __hip_atomic_load(&g_epoch, __ATOMIC_RELAXED, __HIP_MEMORY_SCOPE_AGENT);

  // ---- pack A fragments f32 -> f16: ALL resident, indices compile-time ----
  // Ares[rtl][i]: i<4 = own k-tile okt0+i, i>=4 = partner k-tile pkt0+(i-4)
  uint4 Ares[4][8];
#pragma unroll
  for (int rtl = 0; rtl < 4; ++rtl) {
    const int u = X * 128 + (w << 4) + (rtl << 2) + lg;   // global unit of this A-row
    const int orow = (ga << 8) + u;                        // original Whh row
    const float* wr = Whh + (size_t)orow * HD;
#pragma unroll
    for (int i = 0; i < 8; ++i) {
      const int kt = (i < 4) ? (okt0 + i) : (pkt0 + (i - 4));  // compile-time
      const int k0 = (kt << 5) + (kg << 3);
      const float4 x0 = *reinterpret_cast<const float4*>(wr + k0);
      const float4 x1 = *reinterpret_cast<const float4*>(wr + k0 + 4);
      uint4 f;
      f.x = f2h2(x0.x, x0.y); f.y = f2h2(x0.z, x0.w);
      f.z = f2h2(x1.x, x1.y); f.w = f2h2(x1.z, x1.w);
      Ares[rtl][i] = f;
    }
  }
  if (tid < 128)   // full h0 (both halves) into h2[0]
    reinterpret_cast<unsigned int*>(h2[0])[tid] =
        f2h2(h0g[d * HD + 2 * tid], h0g[d * HD + 2 * tid + 1]);
  float c = (tid < 128) ? c0g[d * HD + X * 128 + tid] : 0.0f;
  __syncthreads();

  const float* Pbase = g_P + (size_t)d * TT * NG + 4 * (X * 128 + tid);  // tid<128
  unsigned short*       payW = g_HX + (size_t)((d * 2 + X) * TT) * 128;
  const unsigned short* payR = g_HX + (size_t)((d * 2 + (X ^ 1)) * TT) * 128;
  unsigned int*         flW  = g_FL + (size_t)(d * 2 + X) * TT * 2;
  const unsigned int*   flR  = g_FL + (size_t)(d * 2 + (X ^ 1)) * TT * 2;

  int t = d ? (TT - 1) : 0;
  const int tstep = d ? -1 : 1;
  float4 Pc = {0.f, 0.f, 0.f, 0.f};
  if (tid < 128) Pc = *reinterpret_cast<const float4*>(Pbase + (size_t)t * NG);
  int p = 0;

  for (int it = 0; it < TT; ++it, t += tstep) {
    uint2 fl = {0u, 0u};
    if (it > 0) {  // async poll of partner's step-(it-1) flags; checked in phase B
      const unsigned int* pp = flR + (size_t)(it - 1) * 2;
      asm volatile("global_load_dwordx2 %0, %1, off sc0 sc1"
                   : "=v"(fl) : "v"(pp) : "memory");
      __builtin_amdgcn_sched_barrier(0);
    }

    // ---- phase A: own-half B-frags (LDS broadcast) + own-kt MFMAs (hides flag latency) ----
    f32x4 acc[4] = {{0.f,0.f,0.f,0.f},{0.f,0.f,0.f,0.f},{0.f,0.f,0.f,0.f},{0.f,0.f,0.f,0.f}};
    {
      f16x8 bfo[4];
#pragma unroll
      for (int i = 0; i < 4; ++i)
        bfo[i] = asf16x8(*reinterpret_cast<const uint4*>(
            &h2[p][((okt0 + i) << 5) + (kg << 3)]));
#pragma unroll
      for (int rtl = 0; rtl < 4; ++rtl)
#pragma unroll
        for (int i = 0; i < 4; ++i)
          acc[rtl] = __builtin_amdgcn_mfma_f32_16x16x32_f16(
              asf16x8(Ares[rtl][i]), bfo[i], acc[rtl], 0, 0, 0);
    }

    // ---- phase B: partner-half B-frags ----
    uint4 pb[4];
    if (it == 0) {
#pragma unroll
      for (int i = 0; i < 4; ++i)
        pb[i] = *reinterpret_cast<const uint4*>(&h2[0][((pkt0 + i) << 5) + (kg << 3)]);
    } else {
      asm volatile("s_waitcnt vmcnt(0)" : "+v"(fl) :: "memory");  // tie: no use-before-wait
      __builtin_amdgcn_sched_barrier(0);
      while (fl.x != ep || fl.y != ep) {
        const unsigned int* pp = flR + (size_t)(it - 1) * 2;
        asm volatile("global_load_dwordx2 %0, %1, off sc0 sc1\n\ts_waitcnt vmcnt(0)"
                     : "=v"(fl) : "v"(pp) : "memory");
      }
      const unsigned short* pr = payR + (size_t)(it - 1) * 128 + (kg << 3);
      asm volatile(
          "global_load_dwordx4 %0, %4, off sc0 sc1\n\t"
          "global_load_dwordx4 %1, %4, off offset:64 sc0 sc1\n\t"
          "global_load_dwordx4 %2, %4, off offset:128 sc0 sc1\n\t"
          "global_load_dwordx4 %3, %4, off offset:192 sc0 sc1\n\t"
          "s_waitcnt vmcnt(0)"
          : "=v"(pb[0]), "=v"(pb[1]), "=v"(pb[2]), "=v"(pb[3])
          : "v"(pr) : "memory");
      __builtin_amdgcn_sched_barrier(0);
    }
#pragma unroll
    for (int rtl = 0; rtl < 4; ++rtl)
#pragma unroll
      for (int i = 0; i < 4; ++i)
        acc[rtl] = __builtin_amdgcn_mfma_f32_16x16x32_f16(
            asf16x8(Ares[rtl][4 + i]), asf16x8(pb[i]), acc[rtl], 0, 0, 0);

    // ---- phase D: gates to LDS (D row = kg*4+reg -> local unit w*16+rtl*4+kg) ----
    if (m == 0) {
#pragma unroll
      for (int rtl = 0; rtl < 4; ++rtl)
        *reinterpret_cast<float4*>(gates[(w << 4) + (rtl << 2) + kg]) =
            __builtin_bit_cast(float4, acc[rtl]);
    }
    asm volatile("s_waitcnt lgkmcnt(0)" ::: "memory");
    __builtin_amdgcn_s_barrier();
    __builtin_amdgcn_sched_barrier(0);

    // ---- phase E: cell update, one lane per local unit (tid<128) ----
    if (tid < 128) {
      const float4 gv = *reinterpret_cast<const float4*>(gates[tid]);
      const float gi = gv.x + Pc.x;
      const float gf = gv.y + Pc.y;
      const float gz = gv.z + Pc.z;
      const float go = gv.w + Pc.w;
      c = fsigmoid(gf) * c + fsigmoid(gi) * ftanh(gz);
      const float hh = fsigmoid(go) * ftanh(c);
      const unsigned short hb16 = __builtin_bit_cast(unsigned short, (_Float16)hh);
      // release pattern: payload -> vmcnt(0) -> flag (earliest possible post)
      unsigned short* pw = payW + (size_t)it * 128 + tid;
      asm volatile("global_store_short %0, %1, off sc0 sc1"
                   :: "v"(pw), "v"((unsigned int)hb16) : "memory");
      h2[p ^ 1][X * 128 + tid] = hb16;
      asm volatile("s_waitcnt vmcnt(0)" ::: "memory");
      if (lane == 0) {
        unsigned int* fp = flW + (size_t)it * 2 + w;
        asm volatile("global_store_dword %0, %1, off sc0 sc1"
                     :: "v"(fp), "v"(ep) : "memory");
      }
      g_HS[((size_t)d * TT + t) * HD + X * 128 + tid] = hh;          // f32 for feats
      // reload P for next step: a full step of latency cover
      const int tn = (it + 1 < TT) ? (t + tstep) : t;
      Pc = *reinterpret_cast<const float4*>(Pbase + (size_t)tn * NG);
    }
    p ^= 1;
    // barrier 2: h2 ready for next step's own-half reads (LDS-only drain)
    asm volatile("s_waitcnt lgkmcnt(0)" ::: "memory");
    __builtin_amdgcn_s_barrier();
    __builtin_amdgcn_sched_barrier(0);
  }
}

__global__ __launch_bounds__(512, 2) void k_rec(
    const float* __restrict__ WhhF, const float* __restrict__ WhhB,
    const float* __restrict__ h0g, const float* __restrict__ c0g)
{
  __shared__ __align__(16) unsigned short h2[2][256];  // f16 h (full 256), double buffered
  __shared__ __align__(16) float gates[128][4];        // (i,f,g,o) per local unit

  const int bid = blockIdx.x;
  const int d = bid >> 1, x = bid & 1;
  const float* __restrict__ Whh = d ? WhhB : WhhF;
  if (x == 0) rec_body<0>(d, Whh, h0g, c0g, h2, gates);
  else        rec_body<1>(d, Whh, h0g, c0g, h2, gates);
}

// ---------------- K3: feats = [hf;hb] @ Wlin^T + blin (pure f32) ----------------
__global__ __launch_bounds__(256) void k_feats(
    const float* __restrict__ Wlin, const float* __restrict__ blin)
{
  const int gid = blockIdx.x * 256 + threadIdx.x;
  if (gid >= TT * NC) return;
  const int t = gid / NC, cc = gid - t * NC;
  const float* hf = g_HS + (size_t)t * HD;
  const float* hb = g_HS + ((size_t)TT + t) * HD;
  const float* wr = Wlin + cc * 512;
  float acc = blin[cc];
  for (int j = 0; j < HD; j += 4) {
    const float4 w = *reinterpret_cast<const float4*>(wr + j);
    acc += w.x * hf[j] + w.y * hf[j + 1] + w.z * hf[j + 2] + w.w * hf[j + 3];
  }
  for (int j = 0; j < HD; j += 4) {
    const float4 w = *reinterpret_cast<const float4*>(wr + 256 + j);
    acc += w.x * hb[j] + w.y * hb[j + 1] + w.z * hb[j + 2] + w.w * hb[j + 3];
  }
  g_FE[gid] = acc;
}

// ---------------- K4: Viterbi + backtrace (single wave); f32 in/out ----------------
__global__ __launch_bounds__(64) void k_vit(
    const float* __restrict__ trans, float* __restrict__ out)
{
  const int lane = threadIdx.x;
  const bool act = lane < NC;
  __shared__ unsigned char bp[TT][NC];
  float Trow[NC];
#pragma unroll
  for (int i = 0; i < NC; ++i) Trow[i] = act ? trans[lane * NC + i] : NEGV;
  float fv[NC];
#pragma unroll
  for (int i = 0; i < NC; ++i) fv[i] = (i == 10) ? 0.0f : NEGV;  // START=10

  float f0 = act ? g_FE[lane] : 0.0f;                 // 2-deep FE prefetch
  float f1 = act ? g_FE[NC + lane] : 0.0f;
  for (int t = 0; t < TT; ++t) {
    const float feat = f0;
    f0 = f1;
    f1 = (act && t + 2 < TT) ? g_FE[(t + 2) * NC + lane] : 0.0f;
    float best = fv[0] + Trow[0]; int bi = 0;
#pragma unroll
    for (int i = 1; i < NC; ++i) {
      const float s = fv[i] + Trow[i];
      if (s > best) { best = s; bi = i; }   // strict > == jnp first-max tiebreak
    }
    if (act) bp[t][lane] = (unsigned char)bi;
    const float nf = best + feat;
#pragma unroll
    for (int i = 0; i < NC; ++i) fv[i] = __shfl(nf, i);
  }
  // terminal = fv + transitions[STOP=11] (row 11)
  const float term = act ? (fv[lane] + trans[11 * NC + lane]) : -3.0e38f;
  float tv[NC];
#pragma unroll
  for (int i = 0; i < NC; ++i) tv[i] = __shfl(term, i);
  if (lane == 0) {
    float bs = tv[0]; int bt = 0;
#pragma unroll
    for (int i = 1; i < NC; ++i) if (tv[i] > bs) { bs = tv[i]; bt = i; }
    out[0] = bs;                             // f32 path_score
    int tag = bt;
    for (int t = TT - 1; t >= 0; --t) {
      out[1 + t] = (float)tag;               // path tags as f32
      tag = bp[t][tag];
    }
  }
}

extern "C" void kernel_launch(void* const* d_in, const int* in_sizes, int n_in,
                              void* d_out, int out_size, void* d_ws, size_t ws_size,
                              hipStream_t stream) {
  const int*   sent = (const int*)d_in[0];
  const float* emb  = (const float*)d_in[1];
  const float* WihF = (const float*)d_in[2];
  const float* WhhF = (const float*)d_in[3];
  const float* bihF = (const float*)d_in[4];
  const float* bhhF = (const float*)d_in[5];
  const float* WihB = (const float*)d_in[6];
  const float* WhhB = (const float*)d_in[7];
  const float* bihB = (const float*)d_in[8];
  const float* bhhB = (const float*)d_in[9];
  const float* Wlin = (const float*)d_in[10];
  const float* blin = (const float*)d_in[11];
  const float* h0g  = (const float*)d_in[12];
  const float* c0g  = (const float*)d_in[13];
  const float* trans= (const float*)d_in[14];
  (void)d_ws; (void)ws_size; (void)in_sizes; (void)n_in; (void)out_size;

  k_input<<<dim3(2 * (TT / 16)), dim3(256), 0, stream>>>(
      sent, emb, WihF, bihF, bhhF, WihB, bihB, bhhB);

  k_rec<<<dim3(4), dim3(512), 0, stream>>>(WhhF, WhhB, h0g, c0g);

  k_feats<<<dim3((TT * NC + 255) / 256), dim3(256), 0, stream>>>(Wlin, blin);

  k_vit<<<dim3(1), dim3(64), 0, stream>>>(trans, (float*)d_out);
}